// Round 2
// baseline (821.148 us; speedup 1.0000x reference)
//
#include <hip/hip_runtime.h>

// 2-layer GCN on MI355X — gather (pull) formulation, no float atomics.
// out = relu(Ahat @ relu(Ahat @ (x@W1) + b1) @ W2 + b2),
// Ahat = D^-1/2 (A+I) D^-1/2.
//
// Pipeline:
//   1. cnt[dst]++            (int histogram == in-degree)
//   2. single-block exclusive scan -> off[], dis[]=rsqrt(deg+1), cursor (reuses cnt)
//   3. place: ssrc[atomicAdd(cursor[dst])] = src   (edges bucketed by dst)
//   4. h1 = x @ W1
//   5. gather64: agg1[i] = dis[i] * (sum_e dis[src] h1[src] + dis[i] h1[i])
//   6. h2 = relu(agg1 + b1) @ W2
//   7. gather32 (fused bias+relu): out[i] = relu(dis[i]*(...) + b2)

__global__ __launch_bounds__(256) void k_zero(int* __restrict__ p, int n) {
  int i = blockIdx.x * 256 + threadIdx.x;
  if (i < n) p[i] = 0;
}

__global__ __launch_bounds__(256) void k_hist(const int* __restrict__ dst,
                                              int* __restrict__ cnt, int E) {
  int e = blockIdx.x * 256 + threadIdx.x;
  if (e < E) atomicAdd(&cnt[dst[e]], 1);
}

// Single block, 1024 threads: exclusive scan of cnt -> off, dis = rsqrt(cnt+1),
// cnt becomes the placement cursor (copy of off).
__global__ __launch_bounds__(1024) void k_scan(int* __restrict__ cnt,
                                               int* __restrict__ off,
                                               float* __restrict__ dis,
                                               int n, int E) {
  __shared__ int lds[1024];
  int t = threadIdx.x;
  int C = (n + 1023) / 1024;
  int b0 = t * C;
  int e0 = min(b0 + C, n);
  int s = 0;
  for (int j = b0; j < e0; ++j) s += cnt[j];
  lds[t] = s;
  __syncthreads();
  for (int d = 1; d < 1024; d <<= 1) {
    int v = (t >= d) ? lds[t - d] : 0;
    __syncthreads();
    lds[t] += v;
    __syncthreads();
  }
  int run = (t == 0) ? 0 : lds[t - 1];
  for (int j = b0; j < e0; ++j) {
    int c = cnt[j];
    off[j] = run;
    dis[j] = rsqrtf((float)(c + 1));
    cnt[j] = run;  // cursor
    run += c;
  }
  if (t == 1023) off[n] = E;
}

__global__ __launch_bounds__(256) void k_place(const int* __restrict__ src,
                                               const int* __restrict__ dst,
                                               int* __restrict__ cur,
                                               int* __restrict__ ssrc, int E) {
  int e = blockIdx.x * 256 + threadIdx.x;
  if (e < E) {
    int pos = atomicAdd(&cur[dst[e]], 1);
    ssrc[pos] = src[e];
  }
}

// H[n,64] = X[n,64] @ W[64,64].  One wave per row; lane = out column.
__global__ __launch_bounds__(256) void k_gemm64(const float* __restrict__ X,
                                                const float* __restrict__ W,
                                                float* __restrict__ H, int n) {
  __shared__ float Wl[64 * 64];
  int tid = threadIdx.x;
#pragma unroll
  for (int i = 0; i < 16; ++i) Wl[i * 256 + tid] = W[i * 256 + tid];
  __syncthreads();
  int lane = tid & 63;
  int wv   = tid >> 6;
  int base = blockIdx.x * 64;
  for (int it = 0; it < 16; ++it) {
    int row = base + it * 4 + wv;
    if (row >= n) return;
    float xv = X[(size_t)row * 64 + lane];
    float acc = 0.f;
#pragma unroll
    for (int k = 0; k < 64; ++k)
      acc = fmaf(__shfl(xv, k), Wl[k * 64 + lane], acc);
    H[(size_t)row * 64 + lane] = acc;
  }
}

// H2[n,32] = relu(A[n,64] + b1) @ W2[64,32].
__global__ __launch_bounds__(256) void k_gemm32(const float* __restrict__ A,
                                                const float* __restrict__ b1,
                                                const float* __restrict__ W,
                                                float* __restrict__ H, int n) {
  __shared__ float Wl[64 * 32];
  int tid = threadIdx.x;
#pragma unroll
  for (int i = 0; i < 8; ++i) Wl[i * 256 + tid] = W[i * 256 + tid];
  __syncthreads();
  int col = tid & 31;
  int sub = (tid >> 5) & 1;
  int wv  = tid >> 6;
  float b_lo = b1[col];
  float b_hi = b1[col + 32];
  int base = blockIdx.x * 64;
  for (int it = 0; it < 8; ++it) {
    int row = base + it * 8 + wv * 2 + sub;
    if (row >= n) return;
    float a0 = fmaxf(A[(size_t)row * 64 + col]      + b_lo, 0.f);
    float a1 = fmaxf(A[(size_t)row * 64 + 32 + col] + b_hi, 0.f);
    float acc = 0.f;
#pragma unroll
    for (int k = 0; k < 32; ++k) {
      acc = fmaf(__shfl(a0, k, 32), Wl[k * 32 + col], acc);
      acc = fmaf(__shfl(a1, k, 32), Wl[(k + 32) * 32 + col], acc);
    }
    H[(size_t)row * 32 + col] = acc;
  }
}

// One wave per node, lane = feature (F=64). No atomics.
__global__ __launch_bounds__(256) void k_gather64(const int* __restrict__ off,
                                                  const int* __restrict__ ssrc,
                                                  const float* __restrict__ dis,
                                                  const float* __restrict__ H,
                                                  float* __restrict__ agg, int n) {
  int lane = threadIdx.x & 63;
  int i = blockIdx.x * 4 + (threadIdx.x >> 6);
  if (i >= n) return;
  int beg = off[i], end = off[i + 1];
  float di  = dis[i];
  float sum = di * H[(size_t)i * 64 + lane];  // self-loop
  int e = beg;
  for (; e + 1 < end; e += 2) {
    int s0 = ssrc[e], s1 = ssrc[e + 1];
    float d0 = dis[s0], d1 = dis[s1];
    sum = fmaf(d0, H[(size_t)s0 * 64 + lane], sum);
    sum = fmaf(d1, H[(size_t)s1 * 64 + lane], sum);
  }
  if (e < end) {
    int s = ssrc[e];
    sum = fmaf(dis[s], H[(size_t)s * 64 + lane], sum);
  }
  agg[(size_t)i * 64 + lane] = di * sum;
}

// One wave per node, F=32: lane halves split the edge list, shfl-combine.
// Fused epilogue: out = relu(dis[i]*sum + b2).
__global__ __launch_bounds__(256) void k_gather32(const int* __restrict__ off,
                                                  const int* __restrict__ ssrc,
                                                  const float* __restrict__ dis,
                                                  const float* __restrict__ H,
                                                  const float* __restrict__ b2,
                                                  float* __restrict__ out, int n) {
  int lane = threadIdx.x & 63;
  int col  = lane & 31;
  int half = lane >> 5;  // 0/1: even/odd edges
  int i = blockIdx.x * 4 + (threadIdx.x >> 6);
  if (i >= n) return;
  int beg = off[i], end = off[i + 1];
  float di  = dis[i];
  float sum = half ? 0.f : di * H[(size_t)i * 32 + col];  // self-loop once
  for (int e = beg + half; e < end; e += 2) {
    int s = ssrc[e];
    sum = fmaf(dis[s], H[(size_t)s * 32 + col], sum);
  }
  sum += __shfl_xor(sum, 32);
  if (half == 0) out[(size_t)i * 32 + col] = fmaxf(fmaf(di, sum, b2[col]), 0.f);
}

extern "C" void kernel_launch(void* const* d_in, const int* in_sizes, int n_in,
                              void* d_out, int out_size, void* d_ws, size_t ws_size,
                              hipStream_t stream) {
  const float* x  = (const float*)d_in[0];
  const int*   ei = (const int*)d_in[1];
  const float* W1 = (const float*)d_in[2];
  const float* b1 = (const float*)d_in[3];
  const float* W2 = (const float*)d_in[4];
  const float* b2 = (const float*)d_in[5];
  float* out = (float*)d_out;

  const int n = in_sizes[0] / 64;
  const int E = in_sizes[1] / 2;
  const int* src = ei;
  const int* dst = ei + E;

  // ws layout: cnt[n] | off[n+1] | dis[n] | ssrc[E] | h1[n*64] | agg1[n*64]
  // h2[n*32] aliases h1 (dead after gather64).
  int*   cnt  = (int*)d_ws;
  int*   off  = cnt + n;
  float* dis  = (float*)(off + n + 1);
  int*   ssrc = (int*)(dis + n);
  float* h1   = (float*)(ssrc + E);
  float* agg1 = h1 + (size_t)n * 64;
  float* h2   = h1;

  auto cdiv = [](long long a, long long b) { return (unsigned)((a + b - 1) / b); };
  dim3 B(256);

  k_zero    <<<cdiv(n, 256), B, 0, stream>>>(cnt, n);
  k_hist    <<<cdiv(E, 256), B, 0, stream>>>(dst, cnt, E);
  k_scan    <<<1, 1024, 0, stream>>>(cnt, off, dis, n, E);
  k_place   <<<cdiv(E, 256), B, 0, stream>>>(src, dst, cnt, ssrc, E);

  k_gemm64  <<<cdiv(n, 64), B, 0, stream>>>(x, W1, h1, n);
  k_gather64<<<cdiv(n, 4),  B, 0, stream>>>(off, ssrc, dis, h1, agg1, n);

  k_gemm32  <<<cdiv(n, 64), B, 0, stream>>>(agg1, b1, W2, h2, n);
  k_gather32<<<cdiv(n, 4),  B, 0, stream>>>(off, ssrc, dis, h2, b2, out, n);
}

// Round 3
// 550.891 us; speedup vs baseline: 1.4906x; 1.4906x over previous
//
#include <hip/hip_runtime.h>

// 2-layer GCN on MI355X — gather (pull) formulation, no float atomics.
// out = relu(Ahat @ relu(Ahat @ (x@W1) + b1) @ W2 + b2),
// Ahat = D^-1/2 (A+I) D^-1/2.
//
// Pipeline:
//   1. cnt[dst]++                     (int histogram == in-degree)
//   2. hierarchical exclusive scan    (k_bsum -> k_bscan -> k_finalize)
//      -> off[], dis[]=rsqrt(deg+1), cursor (reuses cnt)
//   3. place: ssrc[atomicAdd(cursor[dst])] = src   (edges bucketed by dst)
//   4. h1 = x @ W1
//   5. gather64: agg1[i] = dis[i] * (sum_e dis[src] h1[src] + dis[i] h1[i])
//   6. h2 = relu(agg1 + b1) @ W2
//   7. gather32 (fused bias+relu): out[i] = relu(dis[i]*(...) + b2)

#define SCAN_CHUNK 1024  // elements per block in the scan hierarchy

__global__ __launch_bounds__(256) void k_zero(int* __restrict__ p, int n) {
  int i = blockIdx.x * 256 + threadIdx.x;
  if (i < n) p[i] = 0;
}

__global__ __launch_bounds__(256) void k_hist(const int* __restrict__ dst,
                                              int* __restrict__ cnt, int E) {
  int e = blockIdx.x * 256 + threadIdx.x;
  if (e < E) atomicAdd(&cnt[dst[e]], 1);
}

// A: per-block sums of cnt (4 elements/thread).
__global__ __launch_bounds__(256) void k_bsum(const int* __restrict__ cnt,
                                              int* __restrict__ bsum, int n) {
  int base = blockIdx.x * SCAN_CHUNK + threadIdx.x * 4;
  int s = 0;
  if (base + 3 < n) {
    int4 v = *(const int4*)(cnt + base);
    s = v.x + v.y + v.z + v.w;
  } else {
#pragma unroll
    for (int j = 0; j < 4; ++j)
      if (base + j < n) s += cnt[base + j];
  }
#pragma unroll
  for (int d = 1; d < 64; d <<= 1) s += __shfl_xor(s, d);
  __shared__ int ws[4];
  if ((threadIdx.x & 63) == 0) ws[threadIdx.x >> 6] = s;
  __syncthreads();
  if (threadIdx.x == 0) bsum[blockIdx.x] = ws[0] + ws[1] + ws[2] + ws[3];
}

// B: single-block exclusive scan of bsum (nb <= 1024).
__global__ __launch_bounds__(1024) void k_bscan(int* __restrict__ bsum, int nb) {
  __shared__ int lds[1024];
  int t = threadIdx.x;
  int v = (t < nb) ? bsum[t] : 0;
  lds[t] = v;
  __syncthreads();
  for (int d = 1; d < 1024; d <<= 1) {
    int u = (t >= d) ? lds[t - d] : 0;
    __syncthreads();
    lds[t] += u;
    __syncthreads();
  }
  if (t < nb) bsum[t] = lds[t] - v;  // exclusive
}

// C: in-block exclusive scan + block prefix; emit off, dis, cursor.
__global__ __launch_bounds__(256) void k_finalize(int* __restrict__ cnt,
                                                  const int* __restrict__ bsum,
                                                  int* __restrict__ off,
                                                  float* __restrict__ dis,
                                                  int n, int E) {
  int t = threadIdx.x;
  int lane = t & 63, wv = t >> 6;
  int base = blockIdx.x * SCAN_CHUNK + t * 4;
  int c[4];
  int s = 0;
  if (base + 3 < n) {
    int4 v = *(const int4*)(cnt + base);
    c[0] = v.x; c[1] = v.y; c[2] = v.z; c[3] = v.w;
    s = v.x + v.y + v.z + v.w;
  } else {
#pragma unroll
    for (int j = 0; j < 4; ++j) {
      c[j] = (base + j < n) ? cnt[base + j] : 0;
      s += c[j];
    }
  }
  // inclusive wave scan of per-thread sums
  int inc = s;
#pragma unroll
  for (int d = 1; d < 64; d <<= 1) {
    int u = __shfl_up(inc, d);
    if (lane >= d) inc += u;
  }
  __shared__ int wsum[4];
  if (lane == 63) wsum[wv] = inc;
  __syncthreads();
  int wexc = 0;
  for (int w = 0; w < wv; ++w) wexc += wsum[w];
  int run = bsum[blockIdx.x] + wexc + (inc - s);  // exclusive prefix
#pragma unroll
  for (int j = 0; j < 4; ++j) {
    if (base + j < n) {
      off[base + j] = run;
      dis[base + j] = rsqrtf((float)(c[j] + 1));
      cnt[base + j] = run;  // cursor for k_place
      run += c[j];
    }
  }
  if (blockIdx.x == 0 && t == 0) off[n] = E;
}

__global__ __launch_bounds__(256) void k_place(const int* __restrict__ src,
                                               const int* __restrict__ dst,
                                               int* __restrict__ cur,
                                               int* __restrict__ ssrc, int E) {
  int e = blockIdx.x * 256 + threadIdx.x;
  if (e < E) {
    int pos = atomicAdd(&cur[dst[e]], 1);
    ssrc[pos] = src[e];
  }
}

// H[n,64] = X[n,64] @ W[64,64].  One wave per row; lane = out column.
__global__ __launch_bounds__(256) void k_gemm64(const float* __restrict__ X,
                                                const float* __restrict__ W,
                                                float* __restrict__ H, int n) {
  __shared__ float Wl[64 * 64];
  int tid = threadIdx.x;
#pragma unroll
  for (int i = 0; i < 16; ++i) Wl[i * 256 + tid] = W[i * 256 + tid];
  __syncthreads();
  int lane = tid & 63;
  int wv   = tid >> 6;
  int base = blockIdx.x * 64;
  for (int it = 0; it < 16; ++it) {
    int row = base + it * 4 + wv;
    if (row >= n) return;
    float xv = X[(size_t)row * 64 + lane];
    float acc = 0.f;
#pragma unroll
    for (int k = 0; k < 64; ++k)
      acc = fmaf(__shfl(xv, k), Wl[k * 64 + lane], acc);
    H[(size_t)row * 64 + lane] = acc;
  }
}

// H2[n,32] = relu(A[n,64] + b1) @ W2[64,32].
__global__ __launch_bounds__(256) void k_gemm32(const float* __restrict__ A,
                                                const float* __restrict__ b1,
                                                const float* __restrict__ W,
                                                float* __restrict__ H, int n) {
  __shared__ float Wl[64 * 32];
  int tid = threadIdx.x;
#pragma unroll
  for (int i = 0; i < 8; ++i) Wl[i * 256 + tid] = W[i * 256 + tid];
  __syncthreads();
  int col = tid & 31;
  int sub = (tid >> 5) & 1;
  int wv  = tid >> 6;
  float b_lo = b1[col];
  float b_hi = b1[col + 32];
  int base = blockIdx.x * 64;
  for (int it = 0; it < 8; ++it) {
    int row = base + it * 8 + wv * 2 + sub;
    if (row >= n) return;
    float a0 = fmaxf(A[(size_t)row * 64 + col]      + b_lo, 0.f);
    float a1 = fmaxf(A[(size_t)row * 64 + 32 + col] + b_hi, 0.f);
    float acc = 0.f;
#pragma unroll
    for (int k = 0; k < 32; ++k) {
      acc = fmaf(__shfl(a0, k, 32), Wl[k * 32 + col], acc);
      acc = fmaf(__shfl(a1, k, 32), Wl[(k + 32) * 32 + col], acc);
    }
    H[(size_t)row * 32 + col] = acc;
  }
}

// One wave per node, lane = feature (F=64). No atomics.
__global__ __launch_bounds__(256) void k_gather64(const int* __restrict__ off,
                                                  const int* __restrict__ ssrc,
                                                  const float* __restrict__ dis,
                                                  const float* __restrict__ H,
                                                  float* __restrict__ agg, int n) {
  int lane = threadIdx.x & 63;
  int i = blockIdx.x * 4 + (threadIdx.x >> 6);
  if (i >= n) return;
  int beg = off[i], end = off[i + 1];
  float di  = dis[i];
  float sum = di * H[(size_t)i * 64 + lane];  // self-loop
  int e = beg;
  for (; e + 1 < end; e += 2) {
    int s0 = ssrc[e], s1 = ssrc[e + 1];
    float d0 = dis[s0], d1 = dis[s1];
    sum = fmaf(d0, H[(size_t)s0 * 64 + lane], sum);
    sum = fmaf(d1, H[(size_t)s1 * 64 + lane], sum);
  }
  if (e < end) {
    int s = ssrc[e];
    sum = fmaf(dis[s], H[(size_t)s * 64 + lane], sum);
  }
  agg[(size_t)i * 64 + lane] = di * sum;
}

// One wave per node, F=32: lane halves split the edge list, shfl-combine.
// Fused epilogue: out = relu(dis[i]*sum + b2).
__global__ __launch_bounds__(256) void k_gather32(const int* __restrict__ off,
                                                  const int* __restrict__ ssrc,
                                                  const float* __restrict__ dis,
                                                  const float* __restrict__ H,
                                                  const float* __restrict__ b2,
                                                  float* __restrict__ out, int n) {
  int lane = threadIdx.x & 63;
  int col  = lane & 31;
  int half = lane >> 5;  // 0/1: even/odd edges
  int i = blockIdx.x * 4 + (threadIdx.x >> 6);
  if (i >= n) return;
  int beg = off[i], end = off[i + 1];
  float di  = dis[i];
  float sum = half ? 0.f : di * H[(size_t)i * 32 + col];  // self-loop once
  for (int e = beg + half; e < end; e += 2) {
    int s = ssrc[e];
    sum = fmaf(dis[s], H[(size_t)s * 32 + col], sum);
  }
  sum += __shfl_xor(sum, 32);
  if (half == 0) out[(size_t)i * 32 + col] = fmaxf(fmaf(di, sum, b2[col]), 0.f);
}

extern "C" void kernel_launch(void* const* d_in, const int* in_sizes, int n_in,
                              void* d_out, int out_size, void* d_ws, size_t ws_size,
                              hipStream_t stream) {
  const float* x  = (const float*)d_in[0];
  const int*   ei = (const int*)d_in[1];
  const float* W1 = (const float*)d_in[2];
  const float* b1 = (const float*)d_in[3];
  const float* W2 = (const float*)d_in[4];
  const float* b2 = (const float*)d_in[5];
  float* out = (float*)d_out;

  const int n = in_sizes[0] / 64;
  const int E = in_sizes[1] / 2;
  const int* src = ei;
  const int* dst = ei + E;

  const int nb = (n + SCAN_CHUNK - 1) / SCAN_CHUNK;  // scan blocks (<=1024)

  // ws layout: cnt[n] | off[n+1] | dis[n] | bsum[nb] | ssrc[E] | h1[n*64] | agg1[n*64]
  // h2[n*32] aliases h1 (dead after gather64).
  int*   cnt  = (int*)d_ws;
  int*   off  = cnt + n;
  float* dis  = (float*)(off + n + 1);
  int*   bsum = (int*)(dis + n);
  int*   ssrc = bsum + nb;
  float* h1   = (float*)(ssrc + E);
  float* agg1 = h1 + (size_t)n * 64;
  float* h2   = h1;

  auto cdiv = [](long long a, long long b) { return (unsigned)((a + b - 1) / b); };
  dim3 B(256);

  k_zero    <<<cdiv(n, 256), B, 0, stream>>>(cnt, n);
  k_hist    <<<cdiv(E, 256), B, 0, stream>>>(dst, cnt, E);
  k_bsum    <<<nb, B, 0, stream>>>(cnt, bsum, n);
  k_bscan   <<<1, 1024, 0, stream>>>(bsum, nb);
  k_finalize<<<nb, B, 0, stream>>>(cnt, bsum, off, dis, n, E);
  k_place   <<<cdiv(E, 256), B, 0, stream>>>(src, dst, cnt, ssrc, E);

  k_gemm64  <<<cdiv(n, 64), B, 0, stream>>>(x, W1, h1, n);
  k_gather64<<<cdiv(n, 4),  B, 0, stream>>>(off, ssrc, dis, h1, agg1, n);

  k_gemm32  <<<cdiv(n, 64), B, 0, stream>>>(agg1, b1, W2, h2, n);
  k_gather32<<<cdiv(n, 4),  B, 0, stream>>>(off, ssrc, dis, h2, b2, out, n);
}

// Round 5
// 323.518 us; speedup vs baseline: 2.5382x; 1.7028x over previous
//
#include <hip/hip_runtime.h>

// 2-layer GCN on MI355X — gather formulation, two-level counting sort,
// dis-prescaled features, fused gather+gemm for layer 2 input.
//
// out = relu(Ahat @ relu(Ahat @ (x@W1) + b1) @ W2 + b2),
// Ahat = D^-1/2 (A+I) D^-1/2.
//
// Pipeline:
//  1. k_zero_ch     : ch[NB]=0
//  2. k_coarsehist  : ch[b] = #edges with dst>>8 == b   (LDS-privatized)
//  3. k_scanb       : cbase = exscan(ch); gcur = cbase; off[n]=E
//  4. k_binpairs    : pairs[] grouped by coarse bucket (tile-phased, run writes)
//  5. k_finesort    : per bucket: fine hist+scan in LDS -> off[], dis[],
//                     ssrc[] placed in LDS, flushed coalesced
//  6. k_gemm64      : h1p = dis ⊙ (x @ W1)
//  7. k_gather_gemm : per node (1 wave): sum rows of h1p -> agg1 = dis*sum;
//                     p = relu(agg1+b1); h2p = dis ⊙ (p @ W2)   [W2 in LDS]
//                     h2p lives in the (dead) pairs region — NOT h1p (race!)
//  8. k_gather32    : out = relu(dis*(sum h2p rows) + b2)

#define NBMAX 512  // coarse buckets (dst>>8), n<=131072

__global__ __launch_bounds__(512) void k_zero_ch(int* __restrict__ ch, int NB) {
  int t = threadIdx.x;
  if (t < NB) ch[t] = 0;
}

__global__ __launch_bounds__(256) void k_coarsehist(const int* __restrict__ dst,
                                                    int* __restrict__ ch,
                                                    int E, int NB) {
  __shared__ int lh[NBMAX];
  int t = threadIdx.x;
  lh[t] = 0; lh[t + 256] = 0;
  __syncthreads();
  for (int e = blockIdx.x * 256 + t; e < E; e += gridDim.x * 256)
    atomicAdd(&lh[dst[e] >> 8], 1);
  __syncthreads();
  for (int b = t; b < NB; b += 256) {
    int c = lh[b];
    if (c) atomicAdd(&ch[b], c);
  }
}

__global__ __launch_bounds__(512) void k_scanb(const int* __restrict__ ch,
                                               int* __restrict__ cbase,
                                               int* __restrict__ gcur,
                                               int* __restrict__ off,
                                               int NB, int n, int E) {
  __shared__ int lds[512];
  int t = threadIdx.x;
  int v = (t < NB) ? ch[t] : 0;
  lds[t] = v;
  __syncthreads();
  for (int d = 1; d < 512; d <<= 1) {
    int u = (t >= d) ? lds[t - d] : 0;
    __syncthreads();
    lds[t] += u;
    __syncthreads();
  }
  if (t < NB) {
    int exc = lds[t] - v;
    cbase[t] = exc;
    gcur[t]  = exc;
  }
  if (t == 0) off[n] = E;
}

// Tile-phased binning: 4096 edges/block, two passes over the tile.
__global__ __launch_bounds__(256) void k_binpairs(const int* __restrict__ src,
                                                  const int* __restrict__ dst,
                                                  int* __restrict__ gcur,
                                                  int2* __restrict__ pairs,
                                                  int E, int NB) {
  __shared__ int lcnt[NBMAX], gbase[NBMAX];
  int t = threadIdx.x;
  int tile0 = blockIdx.x * 4096;
  lcnt[t] = 0; lcnt[t + 256] = 0;
  __syncthreads();
#pragma unroll
  for (int j = 0; j < 16; ++j) {
    int e = tile0 + j * 256 + t;
    if (e < E) atomicAdd(&lcnt[dst[e] >> 8], 1);
  }
  __syncthreads();
  for (int b = t; b < NB; b += 256) {
    int c = lcnt[b];
    if (c) gbase[b] = atomicAdd(&gcur[b], c);
    lcnt[b] = 0;
  }
  __syncthreads();
#pragma unroll
  for (int j = 0; j < 16; ++j) {
    int e = tile0 + j * 256 + t;
    if (e < E) {
      int dv = dst[e];
      int b  = dv >> 8;
      int slot = atomicAdd(&lcnt[b], 1);
      pairs[gbase[b] + slot] = make_int2(src[e], dv);
    }
  }
}

// One block per coarse bucket: fine sort by dst&255, emit off/dis/ssrc.
__global__ __launch_bounds__(256) void k_finesort(const int2* __restrict__ pairs,
                                                  const int* __restrict__ ch,
                                                  const int* __restrict__ cbase,
                                                  int* __restrict__ off,
                                                  float* __restrict__ dis,
                                                  int* __restrict__ ssrc, int n) {
  __shared__ int hist[256], lcur[256], wsum[4];
  __shared__ int sbuf[8192];
  int b = blockIdx.x;
  int node0 = b << 8;
  int nn = min(256, n - node0);
  int cnt = ch[b], base = cbase[b];
  int t = threadIdx.x;
  hist[t] = 0;
  __syncthreads();
  for (int e = t; e < cnt; e += 256)
    atomicAdd(&hist[pairs[base + e].y & 255], 1);
  __syncthreads();
  int c = hist[t];
  int lane = t & 63, wv = t >> 6;
  int inc = c;
#pragma unroll
  for (int d = 1; d < 64; d <<= 1) {
    int u = __shfl_up(inc, d);
    if (lane >= d) inc += u;
  }
  if (lane == 63) wsum[wv] = inc;
  __syncthreads();
  int pre = 0;
  for (int w = 0; w < wv; ++w) pre += wsum[w];
  int exc = pre + inc - c;  // exclusive prefix within bucket
  if (t < nn) {
    off[node0 + t] = base + exc;
    dis[node0 + t] = rsqrtf((float)(c + 1));
  }
  lcur[t] = exc;
  __syncthreads();
  bool inlds = (cnt <= 8192);
  for (int e = t; e < cnt; e += 256) {
    int2 p = pairs[base + e];
    int slot = atomicAdd(&lcur[p.y & 255], 1);
    if (inlds) sbuf[slot] = p.x;
    else       ssrc[base + slot] = p.x;  // rare fallback
  }
  __syncthreads();
  if (inlds)
    for (int e = t; e < cnt; e += 256) ssrc[base + e] = sbuf[e];
}

// h1p[n,64] = dis ⊙ (X[n,64] @ W[64,64]).  One wave per row.
__global__ __launch_bounds__(256) void k_gemm64(const float* __restrict__ X,
                                                const float* __restrict__ W,
                                                const float* __restrict__ dis,
                                                float* __restrict__ H, int n) {
  __shared__ float Wl[64 * 64];
  int tid = threadIdx.x;
#pragma unroll
  for (int i = 0; i < 16; ++i) Wl[i * 256 + tid] = W[i * 256 + tid];
  __syncthreads();
  int lane = tid & 63;
  int wv   = tid >> 6;
  int base = blockIdx.x * 64;
  for (int it = 0; it < 16; ++it) {
    int row = base + it * 4 + wv;
    if (row >= n) return;
    float xv = X[(size_t)row * 64 + lane];
    float acc = 0.f;
#pragma unroll
    for (int k = 0; k < 64; ++k)
      acc = fmaf(__shfl(xv, k), Wl[k * 64 + lane], acc);
    H[(size_t)row * 64 + lane] = dis[row] * acc;
  }
}

// Fused: gather layer-1 rows, relu(+b1), in-wave 64x32 GEMM, scale by dis.
// One wave per node.  h2p[i,:] = dis[i] * (relu(dis[i]*sum + b1) @ W2)
// h2p is a DISJOINT buffer (reuses dead pairs region), never aliases H.
__global__ __launch_bounds__(256) void k_gather_gemm(const int* __restrict__ off,
                                                     const int* __restrict__ ssrc,
                                                     const float* __restrict__ dis,
                                                     const float* __restrict__ H,
                                                     const float* __restrict__ b1,
                                                     const float* __restrict__ W2,
                                                     float* __restrict__ h2p, int n) {
  __shared__ float Wl[64 * 32];
  __shared__ float b1l[64];
  int tid = threadIdx.x;
#pragma unroll
  for (int i = 0; i < 8; ++i) Wl[i * 256 + tid] = W2[i * 256 + tid];
  if (tid < 64) b1l[tid] = b1[tid];
  __syncthreads();
  int lane = tid & 63;
  int i = blockIdx.x * 4 + (tid >> 6);
  if (i >= n) return;
  int beg = off[i], end = off[i + 1];
  float sum = H[(size_t)i * 64 + lane];  // self-loop (prescaled)
  int e = beg;
  for (; e + 3 < end; e += 4) {
    int s0 = ssrc[e], s1 = ssrc[e + 1], s2 = ssrc[e + 2], s3 = ssrc[e + 3];
    float v0 = H[(size_t)s0 * 64 + lane];
    float v1 = H[(size_t)s1 * 64 + lane];
    float v2 = H[(size_t)s2 * 64 + lane];
    float v3 = H[(size_t)s3 * 64 + lane];
    sum += v0 + v1 + v2 + v3;
  }
  for (; e < end; ++e) sum += H[(size_t)ssrc[e] * 64 + lane];
  float di = dis[i];
  float p = fmaxf(fmaf(di, sum, b1l[lane]), 0.f);  // relu(agg1 + b1), feature=lane
  // in-wave GEMM: half-split over k, combine via xor-shuffle
  int col = lane & 31, half = lane >> 5;
  float acc = 0.f;
#pragma unroll
  for (int k = 0; k < 32; ++k) {
    float pk = __shfl(p, (half << 5) + k);
    acc = fmaf(pk, Wl[(half * 32 + k) * 32 + col], acc);
  }
  acc += __shfl_xor(acc, 32);
  if (half == 0) h2p[(size_t)i * 32 + col] = di * acc;
}

// Final gather over h2p (F=32): lane halves split edges, fused bias+relu.
__global__ __launch_bounds__(256) void k_gather32(const int* __restrict__ off,
                                                  const int* __restrict__ ssrc,
                                                  const float* __restrict__ dis,
                                                  const float* __restrict__ H,
                                                  const float* __restrict__ b2,
                                                  float* __restrict__ out, int n) {
  int lane = threadIdx.x & 63;
  int col  = lane & 31;
  int half = lane >> 5;
  int i = blockIdx.x * 4 + (threadIdx.x >> 6);
  if (i >= n) return;
  int beg = off[i], end = off[i + 1];
  float sum = half ? 0.f : H[(size_t)i * 32 + col];  // self-loop once
  int e = beg + half;
  for (; e + 2 < end; e += 4) {
    int s0 = ssrc[e], s1 = ssrc[e + 2];
    float v0 = H[(size_t)s0 * 32 + col];
    float v1 = H[(size_t)s1 * 32 + col];
    sum += v0 + v1;
  }
  for (; e < end; e += 2) sum += H[(size_t)ssrc[e] * 32 + col];
  sum += __shfl_xor(sum, 32);
  if (half == 0)
    out[(size_t)i * 32 + col] = fmaxf(fmaf(dis[i], sum, b2[col]), 0.f);
}

extern "C" void kernel_launch(void* const* d_in, const int* in_sizes, int n_in,
                              void* d_out, int out_size, void* d_ws, size_t ws_size,
                              hipStream_t stream) {
  const float* x  = (const float*)d_in[0];
  const int*   ei = (const int*)d_in[1];
  const float* W1 = (const float*)d_in[2];
  const float* b1 = (const float*)d_in[3];
  const float* W2 = (const float*)d_in[4];
  const float* b2 = (const float*)d_in[5];
  float* out = (float*)d_out;

  const int n = in_sizes[0] / 64;
  const int E = in_sizes[1] / 2;
  const int* src = ei;
  const int* dst = ei + E;
  const int NB = (n + 255) >> 8;  // coarse buckets (<= NBMAX)

  // ws layout: pairs[E int2] (8B-aligned at base; h2p reuses it after finesort)
  //            | ch[NBMAX] | cbase[NBMAX] | gcur[NBMAX] | off[n+1] | dis[n]
  //            | ssrc[E] | h1p[n*64 f32]
  int2*  pairs = (int2*)d_ws;
  int*   ch    = (int*)(pairs + E);
  int*   cbase = ch + NBMAX;
  int*   gcur  = cbase + NBMAX;
  int*   off   = gcur + NBMAX;
  float* dis   = (float*)(off + n + 1);
  int*   ssrc  = (int*)(dis + n);
  float* h1p   = (float*)(ssrc + E);
  float* h2p   = (float*)pairs;  // n*32 floats == E*2 ints: fits; pairs dead

  auto cdiv = [](long long a, long long b) { return (unsigned)((a + b - 1) / b); };
  dim3 B(256);

  k_zero_ch    <<<1, 512, 0, stream>>>(ch, NB);
  k_coarsehist <<<512, B, 0, stream>>>(dst, ch, E, NB);
  k_scanb      <<<1, 512, 0, stream>>>(ch, cbase, gcur, off, NB, n, E);
  k_binpairs   <<<cdiv(E, 4096), B, 0, stream>>>(src, dst, gcur, pairs, E, NB);
  k_finesort   <<<NB, B, 0, stream>>>(pairs, ch, cbase, off, dis, ssrc, n);

  k_gemm64     <<<cdiv(n, 64), B, 0, stream>>>(x, W1, dis, h1p, n);
  k_gather_gemm<<<cdiv(n, 4),  B, 0, stream>>>(off, ssrc, dis, h1p, b1, W2, h2p, n);
  k_gather32   <<<cdiv(n, 4),  B, 0, stream>>>(off, ssrc, dis, h2p, b2, out, n);
}

// Round 6
// 253.153 us; speedup vs baseline: 3.2437x; 1.2780x over previous
//
#include <hip/hip_runtime.h>

// 2-layer GCN on MI355X — gather formulation, two-level counting sort,
// dis-prescaled features, LDS-tiled register-blocked GEMMs (no shfl GEMMs).
//
// out = relu(Ahat @ relu(Ahat @ (x@W1) + b1) @ W2 + b2),
// Ahat = D^-1/2 (A+I) D^-1/2.
//
// Pipeline:
//  1. k_zero_ch/k_coarsehist/k_scanb/k_binpairs/k_finesort : counting sort
//     -> off[], dis[]=rsqrt(deg+1), ssrc[] (edges bucketed by dst)
//  2. k_gemm64t   : h1p = dis ⊙ (x @ W1)            [tiled, 8x8/thread]
//  3. k_gather64p : p1[i] = relu(dis[i]*(Σ h1p[src] + h1p[i]) + b1)
//  4. k_gemm32t   : h2p = dis ⊙ (p1 @ W2)           [tiled, 8x4/thread]
//  5. k_gather32  : out[i] = relu(dis[i]*(Σ h2p[src] + h2p[i]) + b2)

#define NBMAX 512  // coarse buckets (dst>>8), n<=131072

// ---------------- sort pipeline (unchanged from R4) ----------------

__global__ __launch_bounds__(512) void k_zero_ch(int* __restrict__ ch, int NB) {
  int t = threadIdx.x;
  if (t < NB) ch[t] = 0;
}

__global__ __launch_bounds__(256) void k_coarsehist(const int* __restrict__ dst,
                                                    int* __restrict__ ch,
                                                    int E, int NB) {
  __shared__ int lh[NBMAX];
  int t = threadIdx.x;
  lh[t] = 0; lh[t + 256] = 0;
  __syncthreads();
  for (int e = blockIdx.x * 256 + t; e < E; e += gridDim.x * 256)
    atomicAdd(&lh[dst[e] >> 8], 1);
  __syncthreads();
  for (int b = t; b < NB; b += 256) {
    int c = lh[b];
    if (c) atomicAdd(&ch[b], c);
  }
}

__global__ __launch_bounds__(512) void k_scanb(const int* __restrict__ ch,
                                               int* __restrict__ cbase,
                                               int* __restrict__ gcur,
                                               int* __restrict__ off,
                                               int NB, int n, int E) {
  __shared__ int lds[512];
  int t = threadIdx.x;
  int v = (t < NB) ? ch[t] : 0;
  lds[t] = v;
  __syncthreads();
  for (int d = 1; d < 512; d <<= 1) {
    int u = (t >= d) ? lds[t - d] : 0;
    __syncthreads();
    lds[t] += u;
    __syncthreads();
  }
  if (t < NB) {
    int exc = lds[t] - v;
    cbase[t] = exc;
    gcur[t]  = exc;
  }
  if (t == 0) off[n] = E;
}

__global__ __launch_bounds__(256) void k_binpairs(const int* __restrict__ src,
                                                  const int* __restrict__ dst,
                                                  int* __restrict__ gcur,
                                                  int2* __restrict__ pairs,
                                                  int E, int NB) {
  __shared__ int lcnt[NBMAX], gbase[NBMAX];
  int t = threadIdx.x;
  int tile0 = blockIdx.x * 4096;
  lcnt[t] = 0; lcnt[t + 256] = 0;
  __syncthreads();
#pragma unroll
  for (int j = 0; j < 16; ++j) {
    int e = tile0 + j * 256 + t;
    if (e < E) atomicAdd(&lcnt[dst[e] >> 8], 1);
  }
  __syncthreads();
  for (int b = t; b < NB; b += 256) {
    int c = lcnt[b];
    if (c) gbase[b] = atomicAdd(&gcur[b], c);
    lcnt[b] = 0;
  }
  __syncthreads();
#pragma unroll
  for (int j = 0; j < 16; ++j) {
    int e = tile0 + j * 256 + t;
    if (e < E) {
      int dv = dst[e];
      int b  = dv >> 8;
      int slot = atomicAdd(&lcnt[b], 1);
      pairs[gbase[b] + slot] = make_int2(src[e], dv);
    }
  }
}

__global__ __launch_bounds__(256) void k_finesort(const int2* __restrict__ pairs,
                                                  const int* __restrict__ ch,
                                                  const int* __restrict__ cbase,
                                                  int* __restrict__ off,
                                                  float* __restrict__ dis,
                                                  int* __restrict__ ssrc, int n) {
  __shared__ int hist[256], lcur[256], wsum[4];
  __shared__ int sbuf[8192];
  int b = blockIdx.x;
  int node0 = b << 8;
  int nn = min(256, n - node0);
  int cnt = ch[b], base = cbase[b];
  int t = threadIdx.x;
  hist[t] = 0;
  __syncthreads();
  for (int e = t; e < cnt; e += 256)
    atomicAdd(&hist[pairs[base + e].y & 255], 1);
  __syncthreads();
  int c = hist[t];
  int lane = t & 63, wv = t >> 6;
  int inc = c;
#pragma unroll
  for (int d = 1; d < 64; d <<= 1) {
    int u = __shfl_up(inc, d);
    if (lane >= d) inc += u;
  }
  if (lane == 63) wsum[wv] = inc;
  __syncthreads();
  int pre = 0;
  for (int w = 0; w < wv; ++w) pre += wsum[w];
  int exc = pre + inc - c;
  if (t < nn) {
    off[node0 + t] = base + exc;
    dis[node0 + t] = rsqrtf((float)(c + 1));
  }
  lcur[t] = exc;
  __syncthreads();
  bool inlds = (cnt <= 8192);
  for (int e = t; e < cnt; e += 256) {
    int2 p = pairs[base + e];
    int slot = atomicAdd(&lcur[p.y & 255], 1);
    if (inlds) sbuf[slot] = p.x;
    else       ssrc[base + slot] = p.x;
  }
  __syncthreads();
  if (inlds)
    for (int e = t; e < cnt; e += 256) ssrc[base + e] = sbuf[e];
}

// ---------------- tiled GEMMs ----------------

// XOR-swizzled 16B-unit index for a [rows][64-float] LDS tile:
// conflict-free b128 reads when 8 consecutive-ty lanes read the same column.
__device__ __forceinline__ int swz(int r, int q) {
  return r * 16 + (q ^ ((r >> 3) & 7));
}

// h1p[n,64] = dis ⊙ (X[n,64] @ W[64,64]).
// 128 threads, tile 128 rows x 64 cols, 8x8 per thread.
__global__ __launch_bounds__(128) void k_gemm64t(const float* __restrict__ X,
                                                 const float* __restrict__ W,
                                                 const float* __restrict__ dis,
                                                 float* __restrict__ H, int n) {
  __shared__ float4 Xl[128 * 16];
  __shared__ float4 Wl[64 * 16];
  int t = threadIdx.x;
  int row0 = blockIdx.x * 128;
#pragma unroll
  for (int j = 0; j < 8; ++j) Wl[t + j * 128] = ((const float4*)W)[t + j * 128];
#pragma unroll
  for (int j = 0; j < 16; ++j) {
    int v = t + j * 128;
    int r = v >> 4, q = v & 15;
    int gr = row0 + r;
    float4 val = (gr < n) ? ((const float4*)X)[(size_t)gr * 16 + q]
                          : make_float4(0.f, 0.f, 0.f, 0.f);
    Xl[swz(r, q)] = val;
  }
  __syncthreads();
  int tx = t & 7, ty = t >> 3;  // ty 0..15 (8 rows each), tx 0..7 (8 cols each)
  float acc[8][8];
#pragma unroll
  for (int i = 0; i < 8; ++i)
#pragma unroll
    for (int j = 0; j < 8; ++j) acc[i][j] = 0.f;
  int tysw = ty & 7;
  for (int kq = 0; kq < 16; ++kq) {
    float x_[8][4];
#pragma unroll
    for (int i = 0; i < 8; ++i) {
      float4 v = Xl[(ty * 8 + i) * 16 + (kq ^ tysw)];
      x_[i][0] = v.x; x_[i][1] = v.y; x_[i][2] = v.z; x_[i][3] = v.w;
    }
#pragma unroll
    for (int kk = 0; kk < 4; ++kk) {
      int k = kq * 4 + kk;
      float4 w0 = Wl[k * 16 + tx * 2];
      float4 w1 = Wl[k * 16 + tx * 2 + 1];
      float w_[8] = {w0.x, w0.y, w0.z, w0.w, w1.x, w1.y, w1.z, w1.w};
#pragma unroll
      for (int i = 0; i < 8; ++i)
#pragma unroll
        for (int j = 0; j < 8; ++j)
          acc[i][j] = fmaf(x_[i][kk], w_[j], acc[i][j]);
    }
  }
#pragma unroll
  for (int i = 0; i < 8; ++i) {
    int r = row0 + ty * 8 + i;
    if (r < n) {
      float d = dis[r];
      float4 o0 = make_float4(acc[i][0] * d, acc[i][1] * d, acc[i][2] * d, acc[i][3] * d);
      float4 o1 = make_float4(acc[i][4] * d, acc[i][5] * d, acc[i][6] * d, acc[i][7] * d);
      ((float4*)H)[(size_t)r * 16 + tx * 2]     = o0;
      ((float4*)H)[(size_t)r * 16 + tx * 2 + 1] = o1;
    }
  }
}

// h2p[n,32] = dis ⊙ (P[n,64] @ W2[64,32]).
// 128 threads, tile 128 rows x 32 cols, 8x4 per thread.
__global__ __launch_bounds__(128) void k_gemm32t(const float* __restrict__ P,
                                                 const float* __restrict__ W2,
                                                 const float* __restrict__ dis,
                                                 float* __restrict__ H, int n) {
  __shared__ float4 Pl[128 * 16];
  __shared__ float4 Wl[64 * 8];
  int t = threadIdx.x;
  int row0 = blockIdx.x * 128;
#pragma unroll
  for (int j = 0; j < 4; ++j) Wl[t + j * 128] = ((const float4*)W2)[t + j * 128];
#pragma unroll
  for (int j = 0; j < 16; ++j) {
    int v = t + j * 128;
    int r = v >> 4, q = v & 15;
    int gr = row0 + r;
    float4 val = (gr < n) ? ((const float4*)P)[(size_t)gr * 16 + q]
                          : make_float4(0.f, 0.f, 0.f, 0.f);
    Pl[swz(r, q)] = val;
  }
  __syncthreads();
  int tx = t & 7, ty = t >> 3;  // ty 0..15 (8 rows), tx 0..7 (4 cols each)
  float acc[8][4];
#pragma unroll
  for (int i = 0; i < 8; ++i)
#pragma unroll
    for (int j = 0; j < 4; ++j) acc[i][j] = 0.f;
  int tysw = ty & 7;
  for (int kq = 0; kq < 16; ++kq) {
    float x_[8][4];
#pragma unroll
    for (int i = 0; i < 8; ++i) {
      float4 v = Pl[(ty * 8 + i) * 16 + (kq ^ tysw)];
      x_[i][0] = v.x; x_[i][1] = v.y; x_[i][2] = v.z; x_[i][3] = v.w;
    }
#pragma unroll
    for (int kk = 0; kk < 4; ++kk) {
      int k = kq * 4 + kk;
      float4 w = Wl[k * 8 + tx];
      float w_[4] = {w.x, w.y, w.z, w.w};
#pragma unroll
      for (int i = 0; i < 8; ++i)
#pragma unroll
        for (int j = 0; j < 4; ++j)
          acc[i][j] = fmaf(x_[i][kk], w_[j], acc[i][j]);
    }
  }
#pragma unroll
  for (int i = 0; i < 8; ++i) {
    int r = row0 + ty * 8 + i;
    if (r < n) {
      float d = dis[r];
      float4 o = make_float4(acc[i][0] * d, acc[i][1] * d, acc[i][2] * d, acc[i][3] * d);
      ((float4*)H)[(size_t)r * 8 + tx] = o;
    }
  }
}

// ---------------- gathers ----------------

// One wave per node, lane = feature (F=64); fused relu(di*sum + b1).
__global__ __launch_bounds__(256) void k_gather64p(const int* __restrict__ off,
                                                   const int* __restrict__ ssrc,
                                                   const float* __restrict__ dis,
                                                   const float* __restrict__ H,
                                                   const float* __restrict__ b1,
                                                   float* __restrict__ P, int n) {
  int lane = threadIdx.x & 63;
  int i = blockIdx.x * 4 + (threadIdx.x >> 6);
  if (i >= n) return;
  int beg = off[i], end = off[i + 1];
  float sum = H[(size_t)i * 64 + lane];  // self-loop (prescaled)
  int e = beg;
  for (; e + 3 < end; e += 4) {
    int s0 = ssrc[e], s1 = ssrc[e + 1], s2 = ssrc[e + 2], s3 = ssrc[e + 3];
    float v0 = H[(size_t)s0 * 64 + lane];
    float v1 = H[(size_t)s1 * 64 + lane];
    float v2 = H[(size_t)s2 * 64 + lane];
    float v3 = H[(size_t)s3 * 64 + lane];
    sum += v0 + v1 + v2 + v3;
  }
  for (; e < end; ++e) sum += H[(size_t)ssrc[e] * 64 + lane];
  P[(size_t)i * 64 + lane] = fmaxf(fmaf(dis[i], sum, b1[lane]), 0.f);
}

// One wave per node, F=32: lane halves split edges; fused bias+relu.
__global__ __launch_bounds__(256) void k_gather32(const int* __restrict__ off,
                                                  const int* __restrict__ ssrc,
                                                  const float* __restrict__ dis,
                                                  const float* __restrict__ H,
                                                  const float* __restrict__ b2,
                                                  float* __restrict__ out, int n) {
  int lane = threadIdx.x & 63;
  int col  = lane & 31;
  int half = lane >> 5;
  int i = blockIdx.x * 4 + (threadIdx.x >> 6);
  if (i >= n) return;
  int beg = off[i], end = off[i + 1];
  float sum = half ? 0.f : H[(size_t)i * 32 + col];  // self-loop once
  int e = beg + half;
  for (; e + 2 < end; e += 4) {
    int s0 = ssrc[e], s1 = ssrc[e + 2];
    float v0 = H[(size_t)s0 * 32 + col];
    float v1 = H[(size_t)s1 * 32 + col];
    sum += v0 + v1;
  }
  for (; e < end; e += 2) sum += H[(size_t)ssrc[e] * 32 + col];
  sum += __shfl_xor(sum, 32);
  if (half == 0)
    out[(size_t)i * 32 + col] = fmaxf(fmaf(dis[i], sum, b2[col]), 0.f);
}

extern "C" void kernel_launch(void* const* d_in, const int* in_sizes, int n_in,
                              void* d_out, int out_size, void* d_ws, size_t ws_size,
                              hipStream_t stream) {
  const float* x  = (const float*)d_in[0];
  const int*   ei = (const int*)d_in[1];
  const float* W1 = (const float*)d_in[2];
  const float* b1 = (const float*)d_in[3];
  const float* W2 = (const float*)d_in[4];
  const float* b2 = (const float*)d_in[5];
  float* out = (float*)d_out;

  const int n = in_sizes[0] / 64;
  const int E = in_sizes[1] / 2;
  const int* src = ei;
  const int* dst = ei + E;
  const int NB = (n + 255) >> 8;

  // ws layout: pairs[E int2] | ch[512] | cbase[512] | gcur[512] | off[n+1] |
  //            dis[n] | ssrc[E] | h1p[n*64] | p1[n*64]
  // h2p reuses pairs (dead after finesort) if it fits, else goes after p1.
  int2*  pairs = (int2*)d_ws;
  int*   ch    = (int*)(pairs + E);
  int*   cbase = ch + NBMAX;
  int*   gcur  = cbase + NBMAX;
  int*   off   = gcur + NBMAX;
  float* dis   = (float*)(off + n + 1);
  int*   ssrc  = (int*)(dis + n);
  float* h1p   = (float*)(ssrc + E);
  float* p1    = h1p + (size_t)n * 64;
  float* h2p   = ((size_t)E * 2 >= (size_t)n * 32) ? (float*)pairs
                                                   : (p1 + (size_t)n * 64);

  auto cdiv = [](long long a, long long b) { return (unsigned)((a + b - 1) / b); };
  dim3 B(256);

  k_zero_ch   <<<1, 512, 0, stream>>>(ch, NB);
  k_coarsehist<<<512, B, 0, stream>>>(dst, ch, E, NB);
  k_scanb     <<<1, 512, 0, stream>>>(ch, cbase, gcur, off, NB, n, E);
  k_binpairs  <<<cdiv(E, 4096), B, 0, stream>>>(src, dst, gcur, pairs, E, NB);
  k_finesort  <<<NB, B, 0, stream>>>(pairs, ch, cbase, off, dis, ssrc, n);

  k_gemm64t   <<<cdiv(n, 128), 128, 0, stream>>>(x, W1, dis, h1p, n);
  k_gather64p <<<cdiv(n, 4), B, 0, stream>>>(off, ssrc, dis, h1p, b1, p1, n);
  k_gemm32t   <<<cdiv(n, 128), 128, 0, stream>>>(p1, W2, dis, h2p, n);
  k_gather32  <<<cdiv(n, 4), B, 0, stream>>>(off, ssrc, dis, h2p, b2, out, n);
}

// Round 7
// 218.089 us; speedup vs baseline: 3.7652x; 1.1608x over previous
//
#include <hip/hip_runtime.h>

// 2-layer GCN on MI355X — gather formulation, two-level counting sort,
// dis-prescaled bf16 feature arrays (gather traffic halved), tiled GEMMs.
//
// out = relu(Ahat @ relu(Ahat @ (x@W1) + b1) @ W2 + b2),
// Ahat = D^-1/2 (A+I) D^-1/2.
//
// Pipeline:
//  1. counting sort (packed uint pairs) -> off[], dis[], ssrc[]
//  2. k_gemm64t  : h1b = bf16( dis ⊙ (x @ W1) )         [tiled 8x8/thread]
//  3. k_gather64b: p1[i] = relu(dis[i]*(Σ h1b[src] + h1b[i]) + b1)   (f32)
//  4. k_gemm32t  : h2b = bf16( dis ⊙ (p1 @ W2) )        [tiled 8x4/thread]
//  5. k_gather32b: out[i] = relu(dis[i]*(Σ h2b[src] + h2b[i]) + b2)

#define NBMAX 512  // coarse buckets (dst>>8); requires n < 2^17 (src packs in 24 bits)

// ---- bf16 pack/unpack (round-to-nearest-even) ----
__device__ __forceinline__ unsigned bf16pair(float a, float b) {
  unsigned ua = __float_as_uint(a), ub = __float_as_uint(b);
  ua = (ua + 0x7fffu + ((ua >> 16) & 1u)) >> 16;
  ub = (ub + 0x7fffu + ((ub >> 16) & 1u)) >> 16;
  return ua | (ub << 16);
}
__device__ __forceinline__ float bf_lo(unsigned v) { return __uint_as_float(v << 16); }
__device__ __forceinline__ float bf_hi(unsigned v) { return __uint_as_float(v & 0xffff0000u); }

// ---------------- sort pipeline ----------------

__global__ __launch_bounds__(512) void k_zero_ch(int* __restrict__ ch, int NB) {
  int t = threadIdx.x;
  if (t < NB) ch[t] = 0;
}

__global__ __launch_bounds__(256) void k_coarsehist(const int* __restrict__ dst,
                                                    int* __restrict__ ch,
                                                    int E, int NB) {
  __shared__ int lh[NBMAX];
  int t = threadIdx.x;
  lh[t] = 0; lh[t + 256] = 0;
  __syncthreads();
  for (int e = blockIdx.x * 256 + t; e < E; e += gridDim.x * 256)
    atomicAdd(&lh[dst[e] >> 8], 1);
  __syncthreads();
  for (int b = t; b < NB; b += 256) {
    int c = lh[b];
    if (c) atomicAdd(&ch[b], c);
  }
}

__global__ __launch_bounds__(512) void k_scanb(const int* __restrict__ ch,
                                               int* __restrict__ cbase,
                                               int* __restrict__ gcur,
                                               int* __restrict__ off,
                                               int NB, int n, int E) {
  __shared__ int lds[512];
  int t = threadIdx.x;
  int v = (t < NB) ? ch[t] : 0;
  lds[t] = v;
  __syncthreads();
  for (int d = 1; d < 512; d <<= 1) {
    int u = (t >= d) ? lds[t - d] : 0;
    __syncthreads();
    lds[t] += u;
    __syncthreads();
  }
  if (t < NB) {
    int exc = lds[t] - v;
    cbase[t] = exc;
    gcur[t]  = exc;
  }
  if (t == 0) off[n] = E;
}

// Tile-phased binning: packed (src<<8 | dst&255) runs per coarse bucket.
__global__ __launch_bounds__(256) void k_binpairs(const int* __restrict__ src,
                                                  const int* __restrict__ dst,
                                                  int* __restrict__ gcur,
                                                  unsigned* __restrict__ pairs,
                                                  int E, int NB) {
  __shared__ int lcnt[NBMAX], gbase[NBMAX];
  int t = threadIdx.x;
  int tile0 = blockIdx.x * 4096;
  lcnt[t] = 0; lcnt[t + 256] = 0;
  __syncthreads();
#pragma unroll
  for (int j = 0; j < 16; ++j) {
    int e = tile0 + j * 256 + t;
    if (e < E) atomicAdd(&lcnt[dst[e] >> 8], 1);
  }
  __syncthreads();
  for (int b = t; b < NB; b += 256) {
    int c = lcnt[b];
    if (c) gbase[b] = atomicAdd(&gcur[b], c);
    lcnt[b] = 0;
  }
  __syncthreads();
#pragma unroll
  for (int j = 0; j < 16; ++j) {
    int e = tile0 + j * 256 + t;
    if (e < E) {
      int dv = dst[e];
      int b  = dv >> 8;
      int slot = atomicAdd(&lcnt[b], 1);
      pairs[gbase[b] + slot] = ((unsigned)src[e] << 8) | (unsigned)(dv & 255);
    }
  }
}

__global__ __launch_bounds__(256) void k_finesort(const unsigned* __restrict__ pairs,
                                                  const int* __restrict__ ch,
                                                  const int* __restrict__ cbase,
                                                  int* __restrict__ off,
                                                  float* __restrict__ dis,
                                                  int* __restrict__ ssrc, int n) {
  __shared__ int hist[256], lcur[256], wsum[4];
  __shared__ int sbuf[8192];
  int b = blockIdx.x;
  int node0 = b << 8;
  int nn = min(256, n - node0);
  int cnt = ch[b], base = cbase[b];
  int t = threadIdx.x;
  hist[t] = 0;
  __syncthreads();
  for (int e = t; e < cnt; e += 256)
    atomicAdd(&hist[pairs[base + e] & 255u], 1);
  __syncthreads();
  int c = hist[t];
  int lane = t & 63, wv = t >> 6;
  int inc = c;
#pragma unroll
  for (int d = 1; d < 64; d <<= 1) {
    int u = __shfl_up(inc, d);
    if (lane >= d) inc += u;
  }
  if (lane == 63) wsum[wv] = inc;
  __syncthreads();
  int pre = 0;
  for (int w = 0; w < wv; ++w) pre += wsum[w];
  int exc = pre + inc - c;
  if (t < nn) {
    off[node0 + t] = base + exc;
    dis[node0 + t] = rsqrtf((float)(c + 1));
  }
  lcur[t] = exc;
  __syncthreads();
  bool inlds = (cnt <= 8192);
  for (int e = t; e < cnt; e += 256) {
    unsigned p = pairs[base + e];
    int slot = atomicAdd(&lcur[p & 255u], 1);
    int sv = (int)(p >> 8);
    if (inlds) sbuf[slot] = sv;
    else       ssrc[base + slot] = sv;
  }
  __syncthreads();
  if (inlds)
    for (int e = t; e < cnt; e += 256) ssrc[base + e] = sbuf[e];
}

// ---------------- tiled GEMMs ----------------

__device__ __forceinline__ int swz(int r, int q) {
  return r * 16 + (q ^ ((r >> 3) & 7));
}

// h1b[n,64 bf16] = bf16( dis ⊙ (X[n,64] @ W[64,64]) ).  128 thr, 8x8/thread.
__global__ __launch_bounds__(128) void k_gemm64t(const float* __restrict__ X,
                                                 const float* __restrict__ W,
                                                 const float* __restrict__ dis,
                                                 unsigned* __restrict__ Hb, int n) {
  __shared__ float4 Xl[128 * 16];
  __shared__ float4 Wl[64 * 16];
  int t = threadIdx.x;
  int row0 = blockIdx.x * 128;
#pragma unroll
  for (int j = 0; j < 8; ++j) Wl[t + j * 128] = ((const float4*)W)[t + j * 128];
#pragma unroll
  for (int j = 0; j < 16; ++j) {
    int v = t + j * 128;
    int r = v >> 4, q = v & 15;
    int gr = row0 + r;
    float4 val = (gr < n) ? ((const float4*)X)[(size_t)gr * 16 + q]
                          : make_float4(0.f, 0.f, 0.f, 0.f);
    Xl[swz(r, q)] = val;
  }
  __syncthreads();
  int tx = t & 7, ty = t >> 3;
  float acc[8][8];
#pragma unroll
  for (int i = 0; i < 8; ++i)
#pragma unroll
    for (int j = 0; j < 8; ++j) acc[i][j] = 0.f;
  int tysw = ty & 7;
  for (int kq = 0; kq < 16; ++kq) {
    float x_[8][4];
#pragma unroll
    for (int i = 0; i < 8; ++i) {
      float4 v = Xl[(ty * 8 + i) * 16 + (kq ^ tysw)];
      x_[i][0] = v.x; x_[i][1] = v.y; x_[i][2] = v.z; x_[i][3] = v.w;
    }
#pragma unroll
    for (int kk = 0; kk < 4; ++kk) {
      int k = kq * 4 + kk;
      float4 w0 = Wl[k * 16 + tx * 2];
      float4 w1 = Wl[k * 16 + tx * 2 + 1];
      float w_[8] = {w0.x, w0.y, w0.z, w0.w, w1.x, w1.y, w1.z, w1.w};
#pragma unroll
      for (int i = 0; i < 8; ++i)
#pragma unroll
        for (int j = 0; j < 8; ++j)
          acc[i][j] = fmaf(x_[i][kk], w_[j], acc[i][j]);
    }
  }
#pragma unroll
  for (int i = 0; i < 8; ++i) {
    int r = row0 + ty * 8 + i;
    if (r < n) {
      float d = dis[r];
      uint4 o;
      o.x = bf16pair(acc[i][0] * d, acc[i][1] * d);
      o.y = bf16pair(acc[i][2] * d, acc[i][3] * d);
      o.z = bf16pair(acc[i][4] * d, acc[i][5] * d);
      o.w = bf16pair(acc[i][6] * d, acc[i][7] * d);
      ((uint4*)Hb)[(size_t)r * 8 + tx] = o;
    }
  }
}

// h2b[n,32 bf16] = bf16( dis ⊙ (P[n,64] @ W2[64,32]) ).  128 thr, 8x4/thread.
__global__ __launch_bounds__(128) void k_gemm32t(const float* __restrict__ P,
                                                 const float* __restrict__ W2,
                                                 const float* __restrict__ dis,
                                                 unsigned* __restrict__ Hb, int n) {
  __shared__ float4 Pl[128 * 16];
  __shared__ float4 Wl[64 * 8];
  int t = threadIdx.x;
  int row0 = blockIdx.x * 128;
#pragma unroll
  for (int j = 0; j < 4; ++j) Wl[t + j * 128] = ((const float4*)W2)[t + j * 128];
#pragma unroll
  for (int j = 0; j < 16; ++j) {
    int v = t + j * 128;
    int r = v >> 4, q = v & 15;
    int gr = row0 + r;
    float4 val = (gr < n) ? ((const float4*)P)[(size_t)gr * 16 + q]
                          : make_float4(0.f, 0.f, 0.f, 0.f);
    Pl[swz(r, q)] = val;
  }
  __syncthreads();
  int tx = t & 7, ty = t >> 3;
  float acc[8][4];
#pragma unroll
  for (int i = 0; i < 8; ++i)
#pragma unroll
    for (int j = 0; j < 4; ++j) acc[i][j] = 0.f;
  int tysw = ty & 7;
  for (int kq = 0; kq < 16; ++kq) {
    float x_[8][4];
#pragma unroll
    for (int i = 0; i < 8; ++i) {
      float4 v = Pl[(ty * 8 + i) * 16 + (kq ^ tysw)];
      x_[i][0] = v.x; x_[i][1] = v.y; x_[i][2] = v.z; x_[i][3] = v.w;
    }
#pragma unroll
    for (int kk = 0; kk < 4; ++kk) {
      int k = kq * 4 + kk;
      float4 w = Wl[k * 8 + tx];
      float w_[4] = {w.x, w.y, w.z, w.w};
#pragma unroll
      for (int i = 0; i < 8; ++i)
#pragma unroll
        for (int j = 0; j < 4; ++j)
          acc[i][j] = fmaf(x_[i][kk], w_[j], acc[i][j]);
    }
  }
#pragma unroll
  for (int i = 0; i < 8; ++i) {
    int r = row0 + ty * 8 + i;
    if (r < n) {
      float d = dis[r];
      uint2 o;
      o.x = bf16pair(acc[i][0] * d, acc[i][1] * d);
      o.y = bf16pair(acc[i][2] * d, acc[i][3] * d);
      ((uint2*)Hb)[(size_t)r * 8 + tx] = o;
    }
  }
}

// ---------------- gathers (bf16 rows, f32 accumulate) ----------------

// One wave per node; lane&31 = uint column (2 features), half = edge parity.
// p1[i] = relu(dis[i] * (Σ h1b[src] + h1b[i]) + b1)   — f32 output.
__global__ __launch_bounds__(256) void k_gather64b(const int* __restrict__ off,
                                                   const int* __restrict__ ssrc,
                                                   const float* __restrict__ dis,
                                                   const unsigned* __restrict__ Hb,
                                                   const float* __restrict__ b1,
                                                   float* __restrict__ P, int n) {
  int lane = threadIdx.x & 63;
  int q = lane & 31, half = lane >> 5;
  int i = blockIdx.x * 4 + (threadIdx.x >> 6);
  if (i >= n) return;
  int beg = off[i], end = off[i + 1];
  float s0 = 0.f, s1 = 0.f;
  if (half == 0) {  // self-loop once
    unsigned v = Hb[(size_t)i * 32 + q];
    s0 = bf_lo(v); s1 = bf_hi(v);
  }
  int e = beg + half;
  for (; e + 2 < end; e += 4) {
    unsigned v0 = Hb[(size_t)ssrc[e] * 32 + q];
    unsigned v1 = Hb[(size_t)ssrc[e + 2] * 32 + q];
    s0 += bf_lo(v0) + bf_lo(v1);
    s1 += bf_hi(v0) + bf_hi(v1);
  }
  for (; e < end; e += 2) {
    unsigned v = Hb[(size_t)ssrc[e] * 32 + q];
    s0 += bf_lo(v); s1 += bf_hi(v);
  }
  s0 += __shfl_xor(s0, 32);
  s1 += __shfl_xor(s1, 32);
  if (half == 0) {
    float di = dis[i];
    float2 b = ((const float2*)b1)[q];
    float2 o;
    o.x = fmaxf(fmaf(di, s0, b.x), 0.f);
    o.y = fmaxf(fmaf(di, s1, b.y), 0.f);
    ((float2*)P)[(size_t)i * 32 + q] = o;
  }
}

// One wave per node; lane&15 = uint column (2 features), 4 edge groups.
// out[i] = relu(dis[i] * (Σ h2b[src] + h2b[i]) + b2)   — f32 output.
__global__ __launch_bounds__(256) void k_gather32b(const int* __restrict__ off,
                                                   const int* __restrict__ ssrc,
                                                   const float* __restrict__ dis,
                                                   const unsigned* __restrict__ Hb,
                                                   const float* __restrict__ b2,
                                                   float* __restrict__ out, int n) {
  int lane = threadIdx.x & 63;
  int q = lane & 15, g = lane >> 4;  // g = 0..3
  int i = blockIdx.x * 4 + (threadIdx.x >> 6);
  if (i >= n) return;
  int beg = off[i], end = off[i + 1];
  float s0 = 0.f, s1 = 0.f;
  if (g == 0) {  // self-loop once
    unsigned v = Hb[(size_t)i * 16 + q];
    s0 = bf_lo(v); s1 = bf_hi(v);
  }
  int e = beg + g;
  for (; e + 4 < end; e += 8) {
    unsigned v0 = Hb[(size_t)ssrc[e] * 16 + q];
    unsigned v1 = Hb[(size_t)ssrc[e + 4] * 16 + q];
    s0 += bf_lo(v0) + bf_lo(v1);
    s1 += bf_hi(v0) + bf_hi(v1);
  }
  for (; e < end; e += 4) {
    unsigned v = Hb[(size_t)ssrc[e] * 16 + q];
    s0 += bf_lo(v); s1 += bf_hi(v);
  }
  s0 += __shfl_xor(s0, 16); s1 += __shfl_xor(s1, 16);
  s0 += __shfl_xor(s0, 32); s1 += __shfl_xor(s1, 32);
  if (lane < 16) {
    float di = dis[i];
    float2 b = ((const float2*)b2)[q];
    float2 o;
    o.x = fmaxf(fmaf(di, s0, b.x), 0.f);
    o.y = fmaxf(fmaf(di, s1, b.y), 0.f);
    ((float2*)out)[(size_t)i * 16 + q] = o;
  }
}

extern "C" void kernel_launch(void* const* d_in, const int* in_sizes, int n_in,
                              void* d_out, int out_size, void* d_ws, size_t ws_size,
                              hipStream_t stream) {
  const float* x  = (const float*)d_in[0];
  const int*   ei = (const int*)d_in[1];
  const float* W1 = (const float*)d_in[2];
  const float* b1 = (const float*)d_in[3];
  const float* W2 = (const float*)d_in[4];
  const float* b2 = (const float*)d_in[5];
  float* out = (float*)d_out;

  const int n = in_sizes[0] / 64;
  const int E = in_sizes[1] / 2;
  const int* src = ei;
  const int* dst = ei + E;
  const int NB = (n + 255) >> 8;

  // 16B-aligned workspace carve-out.
  char* wp = (char*)d_ws;
  auto alloc = [&](size_t bytes) {
    char* p = wp;
    wp += (bytes + 15) & ~(size_t)15;
    return (void*)p;
  };
  unsigned* pairs = (unsigned*)alloc((size_t)E * 4);
  int*      ch    = (int*)alloc(NBMAX * 4);
  int*      cbase = (int*)alloc(NBMAX * 4);
  int*      gcur  = (int*)alloc(NBMAX * 4);
  int*      off   = (int*)alloc(((size_t)n + 1) * 4);
  float*    dis   = (float*)alloc((size_t)n * 4);
  int*      ssrc  = (int*)alloc((size_t)E * 4);
  unsigned* h1b   = (unsigned*)alloc((size_t)n * 64 * 2);  // bf16 [n][64]
  float*    p1    = (float*)alloc((size_t)n * 64 * 4);     // f32  [n][64]
  unsigned* h2b   = (unsigned*)alloc((size_t)n * 32 * 2);  // bf16 [n][32]

  auto cdiv = [](long long a, long long b) { return (unsigned)((a + b - 1) / b); };
  dim3 B(256);

  k_zero_ch   <<<1, 512, 0, stream>>>(ch, NB);
  k_coarsehist<<<512, B, 0, stream>>>(dst, ch, E, NB);
  k_scanb     <<<1, 512, 0, stream>>>(ch, cbase, gcur, off, NB, n, E);
  k_binpairs  <<<cdiv(E, 4096), B, 0, stream>>>(src, dst, gcur, pairs, E, NB);
  k_finesort  <<<NB, B, 0, stream>>>(pairs, ch, cbase, off, dis, ssrc, n);

  k_gemm64t   <<<cdiv(n, 128), 128, 0, stream>>>(x, W1, dis, h1b, n);
  k_gather64b <<<cdiv(n, 4), B, 0, stream>>>(off, ssrc, dis, h1b, b1, p1, n);
  k_gemm32t   <<<cdiv(n, 128), 128, 0, stream>>>(p1, W2, dis, h2b, n);
  k_gather32b <<<cdiv(n, 4), B, 0, stream>>>(off, ssrc, dis, h2b, b2, out, n);
}

// Round 8
// 203.039 us; speedup vs baseline: 4.0443x; 1.0741x over previous
//
#include <hip/hip_runtime.h>

// 2-layer GCN on MI355X — gather formulation, two-level counting sort,
// dis-prescaled bf16 feature arrays, tiled GEMMs, MLP-deep gathers.
//
// out = relu(Ahat @ relu(Ahat @ (x@W1) + b1) @ W2 + b2),
// Ahat = D^-1/2 (A+I) D^-1/2.
//
// Pipeline:
//  1. counting sort (packed uint pairs) -> off[], dis[], ssrc[]
//  2. k_gemm64t  : h1b = bf16( dis ⊙ (x @ W1) )         [tiled 8x8/thread]
//  3. k_gather64v: p1[i] = relu(dis[i]*(Σ h1b[src] + h1b[i]) + b1)   (f32)
//  4. k_gemm32t  : h2b = bf16( dis ⊙ (p1 @ W2) )        [tiled 8x4/thread]
//  5. k_gather32v: out[i] = relu(dis[i]*(Σ h2b[src] + h2b[i]) + b2)

#define NBMAX 512  // coarse buckets (dst>>8); requires n < 2^17

// ---- bf16 pack/unpack (round-to-nearest-even) ----
__device__ __forceinline__ unsigned bf16pair(float a, float b) {
  unsigned ua = __float_as_uint(a), ub = __float_as_uint(b);
  ua = (ua + 0x7fffu + ((ua >> 16) & 1u)) >> 16;
  ub = (ub + 0x7fffu + ((ub >> 16) & 1u)) >> 16;
  return ua | (ub << 16);
}
__device__ __forceinline__ float bf_lo(unsigned v) { return __uint_as_float(v << 16); }
__device__ __forceinline__ float bf_hi(unsigned v) { return __uint_as_float(v & 0xffff0000u); }

// ---------------- sort pipeline ----------------

__global__ __launch_bounds__(256) void k_coarsehist(const int* __restrict__ dst,
                                                    int* __restrict__ ch,
                                                    int E, int NB) {
  __shared__ int lh[NBMAX];
  int t = threadIdx.x;
  lh[t] = 0; lh[t + 256] = 0;
  __syncthreads();
  for (int e = blockIdx.x * 256 + t; e < E; e += gridDim.x * 256)
    atomicAdd(&lh[dst[e] >> 8], 1);
  __syncthreads();
  for (int b = t; b < NB; b += 256) {
    int c = lh[b];
    if (c) atomicAdd(&ch[b], c);
  }
}

__global__ __launch_bounds__(512) void k_scanb(const int* __restrict__ ch,
                                               int* __restrict__ cbase,
                                               int* __restrict__ gcur,
                                               int* __restrict__ off,
                                               int NB, int n, int E) {
  __shared__ int lds[512];
  int t = threadIdx.x;
  int v = (t < NB) ? ch[t] : 0;
  lds[t] = v;
  __syncthreads();
  for (int d = 1; d < 512; d <<= 1) {
    int u = (t >= d) ? lds[t - d] : 0;
    __syncthreads();
    lds[t] += u;
    __syncthreads();
  }
  if (t < NB) {
    int exc = lds[t] - v;
    cbase[t] = exc;
    gcur[t]  = exc;
  }
  if (t == 0) off[n] = E;
}

// Tile-phased binning: packed (src<<8 | dst&255) runs per coarse bucket.
__global__ __launch_bounds__(256) void k_binpairs(const int* __restrict__ src,
                                                  const int* __restrict__ dst,
                                                  int* __restrict__ gcur,
                                                  unsigned* __restrict__ pairs,
                                                  int E, int NB) {
  __shared__ int lcnt[NBMAX], gbase[NBMAX];
  int t = threadIdx.x;
  int tile0 = blockIdx.x * 4096;
  lcnt[t] = 0; lcnt[t + 256] = 0;
  __syncthreads();
#pragma unroll
  for (int j = 0; j < 16; ++j) {
    int e = tile0 + j * 256 + t;
    if (e < E) atomicAdd(&lcnt[dst[e] >> 8], 1);
  }
  __syncthreads();
  for (int b = t; b < NB; b += 256) {
    int c = lcnt[b];
    if (c) gbase[b] = atomicAdd(&gcur[b], c);
    lcnt[b] = 0;
  }
  __syncthreads();
#pragma unroll
  for (int j = 0; j < 16; ++j) {
    int e = tile0 + j * 256 + t;
    if (e < E) {
      int dv = dst[e];
      int b  = dv >> 8;
      int slot = atomicAdd(&lcnt[b], 1);
      pairs[gbase[b] + slot] = ((unsigned)src[e] << 8) | (unsigned)(dv & 255);
    }
  }
}

__global__ __launch_bounds__(256) void k_finesort(const unsigned* __restrict__ pairs,
                                                  const int* __restrict__ ch,
                                                  const int* __restrict__ cbase,
                                                  int* __restrict__ off,
                                                  float* __restrict__ dis,
                                                  int* __restrict__ ssrc, int n) {
  __shared__ int hist[256], lcur[256], wsum[4];
  __shared__ int sbuf[8192];
  int b = blockIdx.x;
  int node0 = b << 8;
  int nn = min(256, n - node0);
  int cnt = ch[b], base = cbase[b];
  int t = threadIdx.x;
  hist[t] = 0;
  __syncthreads();
  for (int e = t; e < cnt; e += 256)
    atomicAdd(&hist[pairs[base + e] & 255u], 1);
  __syncthreads();
  int c = hist[t];
  int lane = t & 63, wv = t >> 6;
  int inc = c;
#pragma unroll
  for (int d = 1; d < 64; d <<= 1) {
    int u = __shfl_up(inc, d);
    if (lane >= d) inc += u;
  }
  if (lane == 63) wsum[wv] = inc;
  __syncthreads();
  int pre = 0;
  for (int w = 0; w < wv; ++w) pre += wsum[w];
  int exc = pre + inc - c;
  if (t < nn) {
    off[node0 + t] = base + exc;
    dis[node0 + t] = rsqrtf((float)(c + 1));
  }
  lcur[t] = exc;
  __syncthreads();
  bool inlds = (cnt <= 8192);
  for (int e = t; e < cnt; e += 256) {
    unsigned p = pairs[base + e];
    int slot = atomicAdd(&lcur[p & 255u], 1);
    int sv = (int)(p >> 8);
    if (inlds) sbuf[slot] = sv;
    else       ssrc[base + slot] = sv;
  }
  __syncthreads();
  if (inlds)
    for (int e = t; e < cnt; e += 256) ssrc[base + e] = sbuf[e];
}

// ---------------- tiled GEMMs ----------------

__device__ __forceinline__ int swz(int r, int q) {
  return r * 16 + (q ^ ((r >> 3) & 7));
}

// h1b[n,64 bf16] = bf16( dis ⊙ (X[n,64] @ W[64,64]) ).  128 thr, 8x8/thread.
__global__ __launch_bounds__(128) void k_gemm64t(const float* __restrict__ X,
                                                 const float* __restrict__ W,
                                                 const float* __restrict__ dis,
                                                 unsigned* __restrict__ Hb, int n) {
  __shared__ float4 Xl[128 * 16];
  __shared__ float4 Wl[64 * 16];
  int t = threadIdx.x;
  int row0 = blockIdx.x * 128;
#pragma unroll
  for (int j = 0; j < 8; ++j) Wl[t + j * 128] = ((const float4*)W)[t + j * 128];
#pragma unroll
  for (int j = 0; j < 16; ++j) {
    int v = t + j * 128;
    int r = v >> 4, q = v & 15;
    int gr = row0 + r;
    float4 val = (gr < n) ? ((const float4*)X)[(size_t)gr * 16 + q]
                          : make_float4(0.f, 0.f, 0.f, 0.f);
    Xl[swz(r, q)] = val;
  }
  __syncthreads();
  int tx = t & 7, ty = t >> 3;
  float acc[8][8];
#pragma unroll
  for (int i = 0; i < 8; ++i)
#pragma unroll
    for (int j = 0; j < 8; ++j) acc[i][j] = 0.f;
  int tysw = ty & 7;
  for (int kq = 0; kq < 16; ++kq) {
    float x_[8][4];
#pragma unroll
    for (int i = 0; i < 8; ++i) {
      float4 v = Xl[(ty * 8 + i) * 16 + (kq ^ tysw)];
      x_[i][0] = v.x; x_[i][1] = v.y; x_[i][2] = v.z; x_[i][3] = v.w;
    }
#pragma unroll
    for (int kk = 0; kk < 4; ++kk) {
      int k = kq * 4 + kk;
      float4 w0 = Wl[k * 16 + tx * 2];
      float4 w1 = Wl[k * 16 + tx * 2 + 1];
      float w_[8] = {w0.x, w0.y, w0.z, w0.w, w1.x, w1.y, w1.z, w1.w};
#pragma unroll
      for (int i = 0; i < 8; ++i)
#pragma unroll
        for (int j = 0; j < 8; ++j)
          acc[i][j] = fmaf(x_[i][kk], w_[j], acc[i][j]);
    }
  }
#pragma unroll
  for (int i = 0; i < 8; ++i) {
    int r = row0 + ty * 8 + i;
    if (r < n) {
      float d = dis[r];
      uint4 o;
      o.x = bf16pair(acc[i][0] * d, acc[i][1] * d);
      o.y = bf16pair(acc[i][2] * d, acc[i][3] * d);
      o.z = bf16pair(acc[i][4] * d, acc[i][5] * d);
      o.w = bf16pair(acc[i][6] * d, acc[i][7] * d);
      ((uint4*)Hb)[(size_t)r * 8 + tx] = o;
    }
  }
}

// h2b[n,32 bf16] = bf16( dis ⊙ (P[n,64] @ W2[64,32]) ).  128 thr, 8x4/thread.
__global__ __launch_bounds__(128) void k_gemm32t(const float* __restrict__ P,
                                                 const float* __restrict__ W2,
                                                 const float* __restrict__ dis,
                                                 unsigned* __restrict__ Hb, int n) {
  __shared__ float4 Pl[128 * 16];
  __shared__ float4 Wl[64 * 8];
  int t = threadIdx.x;
  int row0 = blockIdx.x * 128;
#pragma unroll
  for (int j = 0; j < 4; ++j) Wl[t + j * 128] = ((const float4*)W2)[t + j * 128];
#pragma unroll
  for (int j = 0; j < 16; ++j) {
    int v = t + j * 128;
    int r = v >> 4, q = v & 15;
    int gr = row0 + r;
    float4 val = (gr < n) ? ((const float4*)P)[(size_t)gr * 16 + q]
                          : make_float4(0.f, 0.f, 0.f, 0.f);
    Pl[swz(r, q)] = val;
  }
  __syncthreads();
  int tx = t & 7, ty = t >> 3;
  float acc[8][4];
#pragma unroll
  for (int i = 0; i < 8; ++i)
#pragma unroll
    for (int j = 0; j < 4; ++j) acc[i][j] = 0.f;
  int tysw = ty & 7;
  for (int kq = 0; kq < 16; ++kq) {
    float x_[8][4];
#pragma unroll
    for (int i = 0; i < 8; ++i) {
      float4 v = Pl[(ty * 8 + i) * 16 + (kq ^ tysw)];
      x_[i][0] = v.x; x_[i][1] = v.y; x_[i][2] = v.z; x_[i][3] = v.w;
    }
#pragma unroll
    for (int kk = 0; kk < 4; ++kk) {
      int k = kq * 4 + kk;
      float4 w = Wl[k * 8 + tx];
      float w_[4] = {w.x, w.y, w.z, w.w};
#pragma unroll
      for (int i = 0; i < 8; ++i)
#pragma unroll
        for (int j = 0; j < 4; ++j)
          acc[i][j] = fmaf(x_[i][kk], w_[j], acc[i][j]);
    }
  }
#pragma unroll
  for (int i = 0; i < 8; ++i) {
    int r = row0 + ty * 8 + i;
    if (r < n) {
      float d = dis[r];
      uint2 o;
      o.x = bf16pair(acc[i][0] * d, acc[i][1] * d);
      o.y = bf16pair(acc[i][2] * d, acc[i][3] * d);
      ((uint2*)Hb)[(size_t)r * 8 + tx] = o;
    }
  }
}

// ---------------- gathers (bf16 rows, f32 accumulate, deep MLP) ----------------

// One wave per node; lane&15 = uint2 column (4 features), lane>>4 = edge group
// (4 groups). Unroll x2 -> 8 independent row loads in flight per wave.
// p1[i] = relu(dis[i] * (Σ h1b[src] + h1b[i]) + b1)   — f32 output.
__global__ __launch_bounds__(256) void k_gather64v(const int* __restrict__ off,
                                                   const int* __restrict__ ssrc,
                                                   const float* __restrict__ dis,
                                                   const uint2* __restrict__ Hb2,
                                                   const float* __restrict__ b1,
                                                   float* __restrict__ P, int n) {
  int lane = threadIdx.x & 63;
  int q = lane & 15, g = lane >> 4;  // g = 0..3
  int i = blockIdx.x * 4 + (threadIdx.x >> 6);
  if (i >= n) return;
  int beg = off[i], end = off[i + 1];
  float s0 = 0.f, s1 = 0.f, s2 = 0.f, s3 = 0.f;
  if (g == 0) {  // self-loop once
    uint2 v = Hb2[(size_t)i * 16 + q];
    s0 = bf_lo(v.x); s1 = bf_hi(v.x); s2 = bf_lo(v.y); s3 = bf_hi(v.y);
  }
  int e = beg + g;
  for (; e + 4 < end; e += 8) {
    uint2 v0 = Hb2[(size_t)ssrc[e] * 16 + q];
    uint2 v1 = Hb2[(size_t)ssrc[e + 4] * 16 + q];
    s0 += bf_lo(v0.x) + bf_lo(v1.x);
    s1 += bf_hi(v0.x) + bf_hi(v1.x);
    s2 += bf_lo(v0.y) + bf_lo(v1.y);
    s3 += bf_hi(v0.y) + bf_hi(v1.y);
  }
  for (; e < end; e += 4) {
    uint2 v = Hb2[(size_t)ssrc[e] * 16 + q];
    s0 += bf_lo(v.x); s1 += bf_hi(v.x); s2 += bf_lo(v.y); s3 += bf_hi(v.y);
  }
  s0 += __shfl_xor(s0, 16); s1 += __shfl_xor(s1, 16);
  s2 += __shfl_xor(s2, 16); s3 += __shfl_xor(s3, 16);
  s0 += __shfl_xor(s0, 32); s1 += __shfl_xor(s1, 32);
  s2 += __shfl_xor(s2, 32); s3 += __shfl_xor(s3, 32);
  if (lane < 16) {
    float di = dis[i];
    float4 b = ((const float4*)b1)[q];
    float4 o;
    o.x = fmaxf(fmaf(di, s0, b.x), 0.f);
    o.y = fmaxf(fmaf(di, s1, b.y), 0.f);
    o.z = fmaxf(fmaf(di, s2, b.z), 0.f);
    o.w = fmaxf(fmaf(di, s3, b.w), 0.f);
    ((float4*)P)[(size_t)i * 16 + q] = o;
  }
}

// One wave per node; lane&7 = uint2 column (4 features), lane>>3 = edge group
// (8 groups). Up to 16 row loads in flight per wave.
// out[i] = relu(dis[i] * (Σ h2b[src] + h2b[i]) + b2)   — f32 output.
__global__ __launch_bounds__(256) void k_gather32v(const int* __restrict__ off,
                                                   const int* __restrict__ ssrc,
                                                   const float* __restrict__ dis,
                                                   const uint2* __restrict__ Hb2,
                                                   const float* __restrict__ b2,
                                                   float* __restrict__ out, int n) {
  int lane = threadIdx.x & 63;
  int q = lane & 7, g = lane >> 3;  // g = 0..7
  int i = blockIdx.x * 4 + (threadIdx.x >> 6);
  if (i >= n) return;
  int beg = off[i], end = off[i + 1];
  float s0 = 0.f, s1 = 0.f, s2 = 0.f, s3 = 0.f;
  if (g == 0) {  // self-loop once
    uint2 v = Hb2[(size_t)i * 8 + q];
    s0 = bf_lo(v.x); s1 = bf_hi(v.x); s2 = bf_lo(v.y); s3 = bf_hi(v.y);
  }
  int e = beg + g;
  for (; e + 8 < end; e += 16) {
    uint2 v0 = Hb2[(size_t)ssrc[e] * 8 + q];
    uint2 v1 = Hb2[(size_t)ssrc[e + 8] * 8 + q];
    s0 += bf_lo(v0.x) + bf_lo(v1.x);
    s1 += bf_hi(v0.x) + bf_hi(v1.x);
    s2 += bf_lo(v0.y) + bf_lo(v1.y);
    s3 += bf_hi(v0.y) + bf_hi(v1.y);
  }
  for (; e < end; e += 8) {
    uint2 v = Hb2[(size_t)ssrc[e] * 8 + q];
    s0 += bf_lo(v.x); s1 += bf_hi(v.x); s2 += bf_lo(v.y); s3 += bf_hi(v.y);
  }
  s0 += __shfl_xor(s0, 8);  s1 += __shfl_xor(s1, 8);
  s2 += __shfl_xor(s2, 8);  s3 += __shfl_xor(s3, 8);
  s0 += __shfl_xor(s0, 16); s1 += __shfl_xor(s1, 16);
  s2 += __shfl_xor(s2, 16); s3 += __shfl_xor(s3, 16);
  s0 += __shfl_xor(s0, 32); s1 += __shfl_xor(s1, 32);
  s2 += __shfl_xor(s2, 32); s3 += __shfl_xor(s3, 32);
  if (lane < 8) {
    float di = dis[i];
    float4 b = ((const float4*)b2)[q];
    float4 o;
    o.x = fmaxf(fmaf(di, s0, b.x), 0.f);
    o.y = fmaxf(fmaf(di, s1, b.y), 0.f);
    o.z = fmaxf(fmaf(di, s2, b.z), 0.f);
    o.w = fmaxf(fmaf(di, s3, b.w), 0.f);
    ((float4*)out)[(size_t)i * 8 + q] = o;
  }
}

extern "C" void kernel_launch(void* const* d_in, const int* in_sizes, int n_in,
                              void* d_out, int out_size, void* d_ws, size_t ws_size,
                              hipStream_t stream) {
  const float* x  = (const float*)d_in[0];
  const int*   ei = (const int*)d_in[1];
  const float* W1 = (const float*)d_in[2];
  const float* b1 = (const float*)d_in[3];
  const float* W2 = (const float*)d_in[4];
  const float* b2 = (const float*)d_in[5];
  float* out = (float*)d_out;

  const int n = in_sizes[0] / 64;
  const int E = in_sizes[1] / 2;
  const int* src = ei;
  const int* dst = ei + E;
  const int NB = (n + 255) >> 8;

  // 16B-aligned workspace carve-out.
  char* wp = (char*)d_ws;
  auto alloc = [&](size_t bytes) {
    char* p = wp;
    wp += (bytes + 15) & ~(size_t)15;
    return (void*)p;
  };
  unsigned* pairs = (unsigned*)alloc((size_t)E * 4);
  int*      ch    = (int*)alloc(NBMAX * 4);
  int*      cbase = (int*)alloc(NBMAX * 4);
  int*      gcur  = (int*)alloc(NBMAX * 4);
  int*      off   = (int*)alloc(((size_t)n + 1) * 4);
  float*    dis   = (float*)alloc((size_t)n * 4);
  int*      ssrc  = (int*)alloc((size_t)E * 4);
  unsigned* h1b   = (unsigned*)alloc((size_t)n * 64 * 2);  // bf16 [n][64]
  float*    p1    = (float*)alloc((size_t)n * 64 * 4);     // f32  [n][64]
  unsigned* h2b   = (unsigned*)alloc((size_t)n * 32 * 2);  // bf16 [n][32]

  auto cdiv = [](long long a, long long b) { return (unsigned)((a + b - 1) / b); };
  dim3 B(256);

  hipMemsetAsync(ch, 0, (size_t)NBMAX * 4, stream);
  k_coarsehist<<<512, B, 0, stream>>>(dst, ch, E, NB);
  k_scanb     <<<1, 512, 0, stream>>>(ch, cbase, gcur, off, NB, n, E);
  k_binpairs  <<<cdiv(E, 4096), B, 0, stream>>>(src, dst, gcur, pairs, E, NB);
  k_finesort  <<<NB, B, 0, stream>>>(pairs, ch, cbase, off, dis, ssrc, n);

  k_gemm64t   <<<cdiv(n, 128), 128, 0, stream>>>(x, W1, dis, h1b, n);
  k_gather64v <<<cdiv(n, 4), B, 0, stream>>>(off, ssrc, dis, (const uint2*)h1b, b1, p1, n);
  k_gemm32t   <<<cdiv(n, 128), 128, 0, stream>>>(p1, W2, dis, h2b, n);
  k_gather32v <<<cdiv(n, 4), B, 0, stream>>>(off, ssrc, dis, (const uint2*)h2b, b2, out, n);
}